// Round 13
// baseline (3811.261 us; speedup 1.0000x reference)
//
#include <hip/hip_runtime.h>
#include <stdint.h>

#define NN 4096
#define DF 128
#define NBINS 16384          // fine bins; fits LDS (64 KiB u32)
#define NSLAB 256            // histogram slabs per graph
#define BORUVKA_ROUNDS 12

typedef __attribute__((ext_vector_type(8))) short short8;
typedef __attribute__((ext_vector_type(4))) float floatx4;
typedef __attribute__((ext_vector_type(4))) unsigned short ushort4_t;
typedef __attribute__((ext_vector_type(8))) unsigned short ushort8_t;
typedef __attribute__((ext_vector_type(4))) int int4_t;
typedef __attribute__((ext_vector_type(2))) unsigned uvec2;

// ---------- helpers ----------
__device__ __forceinline__ unsigned bin_of(float v, float scale) {
  if (v < 0.f) v = 0.f;
  unsigned b = (unsigned)(v * scale);
  return b >= (unsigned)NBINS ? (unsigned)(NBINS - 1) : b;
}

// async global->LDS, 16B per lane; dest = wave-uniform base + lane*16
__device__ __forceinline__ void gload16(const unsigned short* g, unsigned short* l) {
  __builtin_amdgcn_global_load_lds(
      (const __attribute__((address_space(1))) void*)g,
      (__attribute__((address_space(3))) void*)l, 16, 0, 0);
}

// ---------- row squared norms for both graphs (fp32, matches reference) ----------
__global__ void k_rownorm(const float* __restrict__ x1, const float* __restrict__ x2,
                          float* __restrict__ sq) {
  int i = blockIdx.x * blockDim.x + threadIdx.x;
  if (i >= 2 * NN) return;
  const float* x = (i < NN) ? x1 : x2;
  int r = i & (NN - 1);
  const float* row = x + (size_t)r * DF;
  float s = 0.f;
  for (int k = 0; k < DF; ++k) s += row[k] * row[k];
  sq[i] = s;
}

// ---------- distance upper bound -> u16 quantization scales ----------
// hdrf: [0..1]=caps(u32), [2]=qscale, [3]=qinv
__global__ __launch_bounds__(256) void k_bound(const float* __restrict__ sq,
                                               float* __restrict__ hdrf) {
  int t = threadIdx.x;
  float m = 0.f;
  for (int i = t; i < 2 * NN; i += 256) m = fmaxf(m, sq[i]);
  for (int off = 32; off > 0; off >>= 1) m = fmaxf(m, __shfl_down(m, off, 64));
  __shared__ float wm[4];
  if ((t & 63) == 0) wm[t >> 6] = m;
  __syncthreads();
  if (t == 0) {
    float mm = fmaxf(fmaxf(wm[0], wm[1]), fmaxf(wm[2], wm[3]));
    float dbound = 2.f * sqrtf(mm);       // d <= |xi|+|xj| <= 2*max|x|
    hdrf[2] = 65535.f / dbound;
    hdrf[3] = dbound / 65535.f;
  }
}

// ---------- split fp32 -> (hi, lo) bf16 for error-compensated MFMA ----------
__global__ void k_split(const float* __restrict__ x1, const float* __restrict__ x2,
                        unsigned short* __restrict__ xh, unsigned short* __restrict__ xl) {
  int i = blockIdx.x * blockDim.x + threadIdx.x;
  if (i >= 2 * NN * DF) return;
  const float* x = (i < NN * DF) ? x1 : x2;
  float v = x[i & (NN * DF - 1)];
  unsigned u = __float_as_uint(v);
  unsigned hu = u & 0xffff0000u;
  float hf = __uint_as_float(hu);
  float lf = v - hf;
  unsigned lu = __float_as_uint(lf) & 0xffff0000u;
  xh[i] = (unsigned short)(hu >> 16);
  xl[i] = (unsigned short)(lu >> 16);
}

// ---------- Boruvka init (compbest + mstcnt only; comp lives in k_boruvka's LDS) ----------
__global__ void k_binit(unsigned long long* __restrict__ compbest,
                        int* __restrict__ mstcnt) {
  int i = blockIdx.x * blockDim.x + threadIdx.x;
  if (i >= 2 * NN) return;
  compbest[i] = ~0ull;
  if ((i & (NN - 1)) == 0) mstcnt[i >> 12] = 0;
}

// ---------- distances via split-bf16 MFMA Gram + per-segment min table ----------
// (R10/R11-proven) prefill stores all 32 per-row 128-col segment minima (u32
// (q<<7)|col_local, plain stores — each (row,segment) produced by exactly one
// tile). R13: TRANSPOSED layout segmin[seg][row] so k_boruvka's thread-per-row
// seg-loop reads are coalesced.
#define SJ 136   // u16 stride for store-stage T: 272 B rows, 16B-aligned
__global__ __launch_bounds__(256) void k_dist(const unsigned short* __restrict__ Xhi,
                                              const unsigned short* __restrict__ Xlo,
                                              const float* __restrict__ sq,
                                              const float* __restrict__ hdrf,
                                              unsigned short* __restrict__ Qbase,
                                              unsigned* __restrict__ segmin_base,
                                              unsigned* __restrict__ caps) {
  int bi = blockIdx.y, bj = blockIdx.x;
  if (bi > bj) return;                       // triangle only
  bool offdiag = (bi != bj);
  int g = blockIdx.z;
  const unsigned short* xh = Xhi + (size_t)g * NN * DF;
  const unsigned short* xl = Xlo + (size_t)g * NN * DF;
  const float* sqg = sq + g * NN;
  unsigned short* Q = Qbase + (size_t)g * NN * NN;
  unsigned* smg = segmin_base + (size_t)g * NN * 32;   // [seg][row]
  float qs = hdrf[2];
  int t = threadIdx.x;
  int w = t >> 6, lane = t & 63;
  int m = lane & 15, quad = lane >> 4;
  int iw = (w >> 1) * 64, jw = (w & 1) * 64;   // wave's local tile offsets
  int i0 = bi * 128 + iw;
  int j0 = bj * 128 + jw;

  __shared__ __align__(16) unsigned short SB[128 * SJ];   // staging, then store-stage T

  int baseRow = (w < 2) ? bi * 128 : bj * 128;
  const unsigned short* src = (w == 0 || w == 2) ? xh : xl;
  unsigned short* ldsPiece = &SB[w * 4096];
  int rsub = lane >> 2;                         // 0..15: row within 16-row chunk
  int kpart = (lane & 3) ^ ((lane >> 3) & 3);   // inverse-swizzled k-slot (source side)
  int fr = (quad ^ ((m >> 1) & 3)) << 3;        // read-side swizzle slot

  floatx4 acc[4][4];
#pragma unroll
  for (int ti = 0; ti < 4; ++ti)
#pragma unroll
    for (int tj = 0; tj < 4; ++tj) acc[ti][tj] = (floatx4){0.f, 0.f, 0.f, 0.f};

  for (int s = 0; s < 4; ++s) {
    int kc = s * 32;
    if (s) __syncthreads();                     // previous slab fully consumed
#pragma unroll
    for (int i = 0; i < 8; ++i) {
      const unsigned short* gp =
          src + (size_t)(baseRow + i * 16 + rsub) * DF + kc + kpart * 8;
      gload16(gp, &ldsPiece[i * 512]);
    }
    __syncthreads();
    short8 ah[4], al[4], bh[4], bl[4];
#pragma unroll
    for (int ti = 0; ti < 4; ++ti) {
      int ra = (iw + ti * 16 + m) * 32 + fr;
      int rb = (jw + ti * 16 + m) * 32 + fr;
      ah[ti] = *(const short8*)&SB[ra];
      al[ti] = *(const short8*)&SB[4096 + ra];
      bh[ti] = *(const short8*)&SB[8192 + rb];
      bl[ti] = *(const short8*)&SB[12288 + rb];
    }
#pragma unroll
    for (int ti = 0; ti < 4; ++ti)
#pragma unroll
      for (int tj = 0; tj < 4; ++tj) {
        acc[ti][tj] = __builtin_amdgcn_mfma_f32_16x16x32_bf16(ah[ti], bh[tj], acc[ti][tj], 0, 0, 0);
        acc[ti][tj] = __builtin_amdgcn_mfma_f32_16x16x32_bf16(ah[ti], bl[tj], acc[ti][tj], 0, 0, 0);
        acc[ti][tj] = __builtin_amdgcn_mfma_f32_16x16x32_bf16(al[ti], bh[tj], acc[ti][tj], 0, 0, 0);
      }
  }

  // C/D layout: col = lane&15 (j), row = quad*4 + reg (i)
  float sqj[4];
#pragma unroll
  for (int tj = 0; tj < 4; ++tj) sqj[tj] = sqg[j0 + tj * 16 + m];
  float mx = 0.f;
  ushort4_t qv[4][4];
#pragma unroll
  for (int ti = 0; ti < 4; ++ti) {
    int ib = i0 + ti * 16 + quad * 4;
    float sqiv[4];
#pragma unroll
    for (int r = 0; r < 4; ++r) sqiv[r] = sqg[ib + r];
#pragma unroll
    for (int tj = 0; tj < 4; ++tj) {
#pragma unroll
      for (int r = 0; r < 4; ++r) {
        float d2 = sqiv[r] + sqj[tj] - 2.f * acc[ti][tj][r];
        d2 = fmaxf(d2, 0.f);
        float d = (d2 > 1e-12f) ? sqrtf(d2) : 0.f;
        mx = fmaxf(mx, d);
        unsigned q = (unsigned)(d * qs + 0.5f);
        if (q > 65535u) q = 65535u;
        qv[ti][tj][r] = (unsigned short)q;
      }
    }
  }

  __syncthreads();   // staging reads done in all waves; SB now reusable as T
  unsigned short* T = SB;
  int sub = t >> 4, l16 = t & 15;
  int l31 = lane & 31, half = lane >> 5;

  // per-row per-segment min from 128 rows of T: two 32-lane halves, one row each,
  // 4 cols/lane (one 8B LDS read), 5-level u32 xor reduce, one plain store.
  // u32 key = (q<<7)|col_local — (q,col) order matches the scan key.
  auto prefill_rows = [&](int rbase, int cbase, int segidx, bool exdiag) {
#pragma unroll 4
    for (int ii = 0; ii < 16; ++ii) {
      int rr = w * 32 + ii * 2 + half;
      uvec2 vv = *(const uvec2*)&T[rr * SJ + l31 * 4];
      int row = rbase + rr;
      unsigned qq[4] = {vv[0] & 0xffffu, vv[0] >> 16, vv[1] & 0xffffu, vv[1] >> 16};
      unsigned kmin = 0xffffffffu;
#pragma unroll
      for (int u = 0; u < 4; ++u) {
        int cl = l31 * 4 + u;                  // col_local 0..127
        if (!exdiag || (cbase + cl) != row) {
          unsigned key = (qq[u] << 7) | (unsigned)cl;   // 23 bits
          if (key < kmin) kmin = key;
        }
      }
#pragma unroll
      for (int off2 = 1; off2 < 32; off2 <<= 1) {
        unsigned o = (unsigned)__shfl_xor((int)kmin, off2, 32);
        if (o < kmin) kmin = o;
      }
      if (l31 == 0) smg[(size_t)segidx * NN + row] = kmin;
    }
  };

  // ---- phase A: transposed layout T[jl][il], dump lower/transposed half ----
#pragma unroll
  for (int ti = 0; ti < 4; ++ti) {
    int il = iw + ti * 16 + quad * 4;
#pragma unroll
    for (int tj = 0; tj < 4; ++tj) {
      int jl = jw + tj * 16 + m;
      *(ushort4_t*)&T[jl * SJ + il] = qv[ti][tj];
    }
  }
  __syncthreads();
#pragma unroll
  for (int k = 0; k < 8; ++k) {
    int jl = k * 16 + sub;
    int4_t v = *(const int4_t*)&T[jl * SJ + l16 * 8];
    *(int4_t*)&Q[(size_t)(bj * 128 + jl) * NN + bi * 128 + l16 * 8] = v;
  }
  // j-side rows (rows = bj-block, cols = bi-block, segment bi); diag excludes j==row
  prefill_rows(bj * 128, bi * 128, bi, !offdiag);

  // ---- phase B (off-diagonal only): normal layout T[il][jl], dump upper half ----
  if (offdiag) {
    __syncthreads();
#pragma unroll
    for (int ti = 0; ti < 4; ++ti) {
      int il = iw + ti * 16 + quad * 4;
#pragma unroll
      for (int tj = 0; tj < 4; ++tj) {
        int jl = jw + tj * 16 + m;
#pragma unroll
        for (int r = 0; r < 4; ++r) T[(il + r) * SJ + jl] = qv[ti][tj][r];
      }
    }
    __syncthreads();
#pragma unroll
    for (int k = 0; k < 8; ++k) {
      int il = k * 16 + sub;
      int4_t v = *(const int4_t*)&T[il * SJ + l16 * 8];
      *(int4_t*)&Q[(size_t)(bi * 128 + il) * NN + bj * 128 + l16 * 8] = v;
    }
    // i-side rows (rows = bi-block, cols = bj-block, segment bj)
    prefill_rows(bi * 128, bj * 128, bj, false);
  }

  for (int off = 32; off > 0; off >>= 1) mx = fmaxf(mx, __shfl_down(mx, off, 64));
  __shared__ float wmax[4];
  if (lane == 0) wmax[w] = mx;
  __syncthreads();
  if (t == 0) {
    float mm = fmaxf(fmaxf(wmax[0], wmax[1]), fmaxf(wmax[2], wmax[3]));
    atomicMax(&caps[g], __float_as_uint(mm));
  }
}

// ---------- R13: whole Boruvka in ONE kernel — one block per graph ----------
// No cross-block communication => no fences/tickets/grid-sync (R3/R4/R12 all
// proved those cost 100-140us+). comp lives in LDS; minedge is thread-per-row
// over the coalesced segmin[seg][row] table (512 KB/graph/round, L2-resident);
// hook is the R9-proven 1024-thread in-block logic. compbest stays global:
// atomicMin (L2) -> __syncthreads drains -> AGENT-scope atomic loads (R12's
// hook coherence recipe, which was correct — absmax 0).
__global__ __launch_bounds__(1024) void k_boruvka(
    const unsigned short* __restrict__ Qbase,
    const unsigned* __restrict__ segmin_base,
    unsigned long long* __restrict__ compbest_base,
    const float* __restrict__ hdrf,
    float* __restrict__ mstw_base,
    int* __restrict__ mstcnt) {
  int g = blockIdx.x;
  int t = threadIdx.x;
  const unsigned* smT = segmin_base + (size_t)g * NN * 32;   // [seg][row]
  const unsigned short* Qg = Qbase + (size_t)g * NN * NN;
  unsigned long long* cb = compbest_base + (size_t)g * NN;
  float* mstw = mstw_base + g * (NN - 1);
  float qinv = hdrf[3];

  __shared__ int comp[NN];
  __shared__ int par[NN];
  __shared__ unsigned char live[NN];
  __shared__ int newcnt;
  for (int i = t; i < NN; i += 1024) comp[i] = i;
  __syncthreads();

  for (int r = 0; r < BORUVKA_ROUNDS; ++r) {
    // ---- minedge: thread per row, serial 32-segment loop ----
    for (int v = t; v < NN; v += 1024) {
      int cv = comp[v];
      unsigned best = 0xffffffffu;   // (q<<12)|col
      unsigned flags = 0;
      unsigned fmin = 0xffffffffu;   // min in-comp segment key
#pragma unroll
      for (int s = 0; s < 32; ++s) {
        unsigned k23 = smT[(size_t)s * NN + v];
        unsigned col = (unsigned)s * 128u + (k23 & 127u);
        unsigned key = ((k23 >> 7) << 12) | col;
        if (comp[col] != cv) {
          if (key < best) best = key;
        } else {
          flags |= 1u << s;
          if (key < fmin) fmin = key;
        }
      }
      if (fmin < best) {
        // fallback: fully scan flagged segments that could hide the true min
        unsigned fl = flags;
        while (fl) {
          int s = __ffs(fl) - 1;
          fl &= fl - 1;
          unsigned k23 = smT[(size_t)s * NN + v];
          unsigned segkey = ((k23 >> 7) << 12) | ((unsigned)s * 128u + (k23 & 127u));
          if (segkey >= best) continue;
          const unsigned short* row = Qg + (size_t)v * NN + s * 128;
          for (int u = 0; u < 128; ++u) {
            int col = s * 128 + u;
            if (comp[col] != cv) {
              unsigned key = ((unsigned)row[u] << 12) | (unsigned)col;
              if (key < best) best = key;
            }
          }
        }
      }
      if (best != 0xffffffffu) {
        unsigned long long b64 = ((unsigned long long)(best >> 12) << 24) |
                                 ((unsigned long long)v << 12) | (best & 0xfffu);
        atomicMin(&cb[cv], b64);
      }
    }
    __syncthreads();                 // drains the atomicMins (vmcnt before barrier)
    if (t == 0) newcnt = 0;
    __syncthreads();

    // ---- hook (R9-proven 1024-thread logic, in-block) ----
    for (int c = t; c < NN; c += 1024) {
      unsigned long long key =
          __hip_atomic_load(&cb[c], __ATOMIC_RELAXED, __HIP_MEMORY_SCOPE_AGENT);
      bool a = (key != ~0ull);
      live[c] = a ? 1 : 0;
      int p = c;
      if (a) p = comp[(int)(key & 0xfffull)];
      par[c] = p;
    }
    __syncthreads();
    // break 2-cycles: smaller label becomes root
    for (int c = t; c < NN; c += 1024) {
      int p = par[c];
      if (p != c && par[p] == c && c < p) par[c] = c;
    }
    __syncthreads();
    // emit one MST weight per hooked component (dequantized)
    for (int c = t; c < NN; c += 1024) {
      if (live[c] && par[c] != c) {
        unsigned long long key =
            __hip_atomic_load(&cb[c], __ATOMIC_RELAXED, __HIP_MEMORY_SCOPE_AGENT);
        float wgt = (float)((unsigned)(key >> 24)) * qinv;
        int slot = atomicAdd(&mstcnt[g], 1);
        mstw[slot] = wgt;
      }
    }
    __syncthreads();
    // pointer jumping until stable (hook forests are shallow: typ 2-4 iters)
    for (;;) {
      int np[NN / 1024];
      bool ch = false;
      int k = 0;
      for (int c = t; c < NN; c += 1024, ++k) {
        int p = par[c];
        int pp = par[p];
        np[k] = pp;
        if (pp != p) ch = true;
      }
      __syncthreads();
      k = 0;
      for (int c = t; c < NN; c += 1024, ++k) par[c] = np[k];
      if (!__syncthreads_or(ch)) break;
    }
    // count roots
    int cnt = 0;
    for (int c = t; c < NN; c += 1024)
      if (live[c] && par[c] == c) cnt++;
    for (int off = 32; off > 0; off >>= 1) cnt += __shfl_down(cnt, off, 64);
    if ((t & 63) == 0 && cnt) atomicAdd(&newcnt, cnt);
    // relabel vertices + reset compbest
    for (int v = t; v < NN; v += 1024) comp[v] = par[comp[v]];
    for (int c = t; c < NN; c += 1024)
      __hip_atomic_store(&cb[c], ~0ull, __ATOMIC_RELAXED, __HIP_MEMORY_SCOPE_AGENT);
    __syncthreads();
    if (newcnt == 1) break;          // uniform (LDS value read post-barrier)
  }
}

// ---------- histogram: per-block LDS hist over upper triangle (u16 D), slab dump ----------
// 16B ushort8 vector loads with scalar head (bit-identical binning).
__global__ __launch_bounds__(256) void k_hist(const unsigned short* __restrict__ Qbase,
                                              const unsigned* __restrict__ caps,
                                              const float* __restrict__ hdrf,
                                              unsigned* __restrict__ Hs) {
  __shared__ unsigned h[NBINS];
  int t = threadIdx.x;
  for (int i = t; i < NBINS; i += 256) h[i] = 0;
  int b = blockIdx.x;
  int g = b >> 8, s = b & (NSLAB - 1);
  const unsigned short* Q = Qbase + (size_t)g * NN * NN;
  float cap = __uint_as_float(caps[g]);
  float capmax = fmaxf(__uint_as_float(caps[0]), __uint_as_float(caps[1]));
  float scale = (float)NBINS / capmax;
  float qinv = hdrf[3];
  __syncthreads();
  for (int p = s; p < NN / 2; p += NSLAB) {
#pragma unroll
    for (int half = 0; half < 2; ++half) {
      int rrow = half ? (NN - 1 - p) : p;
      const unsigned short* row = Q + (size_t)rrow * NN;
      int j0 = rrow + 1;
      int ja = (j0 + 7) & ~7;
      if (t < ja - j0)
        atomicAdd(&h[bin_of(cap - (float)row[j0 + t] * qinv, scale)], 1u);
      int nch = (NN - ja) >> 3;
      for (int c = t; c < nch; c += 256) {
        ushort8_t v8 = *(const ushort8_t*)&row[ja + c * 8];
#pragma unroll
        for (int u = 0; u < 8; ++u)
          atomicAdd(&h[bin_of(cap - (float)v8[u] * qinv, scale)], 1u);
      }
    }
  }
  __syncthreads();
  unsigned* slab = Hs + (size_t)b * NBINS;
  for (int i = t; i < NBINS; i += 256) slab[i] = h[i];
}

// ---------- move tree edges to persistence 0 (slab 0; same dequant grid => exact) ----------
__global__ void k_treefix(const float* __restrict__ twbase, const unsigned* __restrict__ caps,
                          unsigned* __restrict__ Hs) {
  int g = blockIdx.y;
  unsigned* hist = Hs + (size_t)(g * NSLAB) * NBINS;
  float cap = __uint_as_float(caps[g]);
  float capmax = fmaxf(__uint_as_float(caps[0]), __uint_as_float(caps[1]));
  float scale = (float)NBINS / capmax;
  int idx = blockIdx.x * blockDim.x + threadIdx.x;
  if (idx < NN - 1) {
    float w = twbase[g * (NN - 1) + idx];
    atomicSub(&hist[bin_of(cap - w, scale)], 1u);  // may wrap; per-bin total stays >= 0
    atomicAdd(&hist[0], 1u);
  }
}

// ---------- merge 256 slabs per graph -> Hm[2][NBINS] ----------
__global__ __launch_bounds__(256) void k_merge(const unsigned* __restrict__ Hs,
                                               unsigned* __restrict__ Hm) {
  int id = blockIdx.x * 256 + threadIdx.x;  // 0 .. 2*NBINS-1
  int g = id >> 14;
  int i = id & (NBINS - 1);
  const unsigned* base = Hs + (size_t)(g * NSLAB) * NBINS + i;
  unsigned sum = 0;
  for (int s = 0; s < NSLAB; ++s) sum += base[(size_t)s * NBINS];
  Hm[id] = sum;
}

// ---------- W1: single block computes sum |running prefix| * dt ----------
__global__ __launch_bounds__(256) void k_w1(const unsigned* __restrict__ Hm,
                                            const unsigned* __restrict__ caps,
                                            float* __restrict__ out) {
  int t = threadIdx.x;
  const int PB = NBINS / 256;  // 64 bins per thread
  int base = t * PB;
  long long tsum = 0;
  for (int i = 0; i < PB; ++i)
    tsum += (long long)(int)(Hm[base + i] - Hm[NBINS + base + i]);
  int lane = t & 63, wid = t >> 6;
  long long incl = tsum;
  for (int off = 1; off < 64; off <<= 1) {
    long long o = __shfl_up(incl, off, 64);
    if (lane >= off) incl += o;
  }
  __shared__ long long wtot[4];
  if (lane == 63) wtot[wid] = incl;
  __syncthreads();
  long long run = incl - tsum;
  for (int w = 0; w < wid; ++w) run += wtot[w];
  unsigned long long local = 0;
  for (int i = 0; i < PB; ++i) {
    run += (long long)(int)(Hm[base + i] - Hm[NBINS + base + i]);
    local += (unsigned long long)(run < 0 ? -run : run);
  }
  for (int off = 32; off > 0; off >>= 1) local += __shfl_down(local, off, 64);
  __shared__ unsigned long long wl[4];
  if (lane == 0) wl[wid] = local;
  __syncthreads();
  if (t == 0) {
    float capmax = fmaxf(__uint_as_float(caps[0]), __uint_as_float(caps[1]));
    double dt = (double)capmax / (double)NBINS;
    out[0] = (float)((double)(wl[0] + wl[1] + wl[2] + wl[3]) * dt);
  }
}

__global__ void k_fail(float* out) { out[0] = -1234567.0f; }

extern "C" void kernel_launch(void* const* d_in, const int* in_sizes, int n_in,
                              void* d_out, int out_size, void* d_ws, size_t ws_size,
                              hipStream_t stream) {
  const float* x1 = (const float*)d_in[0];
  const float* x2 = (const float*)d_in[2];
  float* out = (float*)d_out;
  char* ws = (char*)d_ws;

  const size_t offQ = 0;                                        // u16 D: 64 MiB
  const size_t offS = 2ull * NN * NN * 2ull;                    // slabs: 32 MiB
  const size_t offHm = offS + 2ull * NSLAB * NBINS * 4ull;      // 128 KiB merged hist
  const size_t offHdr = offHm + 2ull * NBINS * 4ull;            // caps+qscale+qinv
  const size_t offSq = offHdr + 64;
  const size_t offTw = offSq + 2ull * NN * 4ull;
  const size_t offCb = (offTw + 2ull * (NN - 1) * 4ull + 7ull) & ~7ull;
  const size_t offSeg = offCb + 2ull * NN * 8ull;               // segmin: 1 MiB
  const size_t offMeta = offSeg + 2ull * NN * 32ull * 4ull;     // mstcnt[2]
  const size_t needed = offMeta + 64;
  if (ws_size < needed) {
    hipLaunchKernelGGL(k_fail, dim3(1), dim3(1), 0, stream, out);
    return;
  }

  unsigned short* Qbase = (unsigned short*)(ws + offQ);
  unsigned* Hs = (unsigned*)(ws + offS);
  // Xhi/Xlo (4 MiB) transiently live in the slab region (dead before k_hist writes it)
  unsigned short* Xhi = (unsigned short*)(ws + offS);
  unsigned short* Xlo = (unsigned short*)(ws + offS + 2ull * NN * DF * 2ull);
  unsigned* Hm = (unsigned*)(ws + offHm);
  unsigned* caps = (unsigned*)(ws + offHdr);
  float* hdrf = (float*)(ws + offHdr);
  float* sq = (float*)(ws + offSq);
  float* tw = (float*)(ws + offTw);
  unsigned long long* compbest = (unsigned long long*)(ws + offCb);
  unsigned* segmin = (unsigned*)(ws + offSeg);
  int* mstcnt = (int*)(ws + offMeta);

  // zero header (caps; qscale/qinv overwritten by k_bound)
  hipMemsetAsync(ws + offHdr, 0, 64, stream);

  hipLaunchKernelGGL(k_rownorm, dim3((2 * NN + 255) / 256), dim3(256), 0, stream, x1, x2, sq);
  hipLaunchKernelGGL(k_bound, dim3(1), dim3(256), 0, stream, sq, hdrf);
  hipLaunchKernelGGL(k_split, dim3((2 * NN * DF + 255) / 256), dim3(256), 0, stream,
                     x1, x2, Xhi, Xlo);
  hipLaunchKernelGGL(k_binit, dim3((2 * NN + 255) / 256), dim3(256), 0, stream,
                     compbest, mstcnt);
  hipLaunchKernelGGL(k_dist, dim3(NN / 128, NN / 128, 2), dim3(256), 0, stream,
                     Xhi, Xlo, sq, hdrf, Qbase, segmin, caps);
  hipLaunchKernelGGL(k_boruvka, dim3(2), dim3(1024), 0, stream,
                     Qbase, segmin, compbest, hdrf, tw, mstcnt);
  hipLaunchKernelGGL(k_hist, dim3(2 * NSLAB), dim3(256), 0, stream, Qbase, caps, hdrf, Hs);
  hipLaunchKernelGGL(k_treefix, dim3(16, 2), dim3(256), 0, stream, tw, caps, Hs);
  hipLaunchKernelGGL(k_merge, dim3(2 * NBINS / 256), dim3(256), 0, stream, Hs, Hm);
  hipLaunchKernelGGL(k_w1, dim3(1), dim3(256), 0, stream, Hm, caps, out);
}

// Round 14
// 338.860 us; speedup vs baseline: 11.2473x; 11.2473x over previous
//
#include <hip/hip_runtime.h>
#include <stdint.h>

#define NN 4096
#define DF 128
#define NBINS 16384          // fine bins; fits LDS (64 KiB u32)
#define NSLAB 256            // histogram slabs per graph
#define BORUVKA_ROUNDS 12

typedef __attribute__((ext_vector_type(8))) short short8;
typedef __attribute__((ext_vector_type(4))) float floatx4;
typedef __attribute__((ext_vector_type(4))) unsigned short ushort4_t;
typedef __attribute__((ext_vector_type(8))) unsigned short ushort8_t;
typedef __attribute__((ext_vector_type(4))) int int4_t;
typedef __attribute__((ext_vector_type(2))) int ivec2;

// ---------- helpers ----------
__device__ __forceinline__ unsigned bin_of(float v, float scale) {
  if (v < 0.f) v = 0.f;
  unsigned b = (unsigned)(v * scale);
  return b >= (unsigned)NBINS ? (unsigned)(NBINS - 1) : b;
}

// async global->LDS, 16B per lane; dest = wave-uniform base + lane*16
__device__ __forceinline__ void gload16(const unsigned short* g, unsigned short* l) {
  __builtin_amdgcn_global_load_lds(
      (const __attribute__((address_space(1))) void*)g,
      (__attribute__((address_space(3))) void*)l, 16, 0, 0);
}

// ---------- row squared norms for both graphs (fp32, matches reference) ----------
__global__ void k_rownorm(const float* __restrict__ x1, const float* __restrict__ x2,
                          float* __restrict__ sq) {
  int i = blockIdx.x * blockDim.x + threadIdx.x;
  if (i >= 2 * NN) return;
  const float* x = (i < NN) ? x1 : x2;
  int r = i & (NN - 1);
  const float* row = x + (size_t)r * DF;
  float s = 0.f;
  for (int k = 0; k < DF; ++k) s += row[k] * row[k];
  sq[i] = s;
}

// ---------- distance upper bound -> u16 quantization scales ----------
// hdrf: [0..1]=caps(u32), [2]=qscale, [3]=qinv
__global__ __launch_bounds__(256) void k_bound(const float* __restrict__ sq,
                                               float* __restrict__ hdrf) {
  int t = threadIdx.x;
  float m = 0.f;
  for (int i = t; i < 2 * NN; i += 256) m = fmaxf(m, sq[i]);
  for (int off = 32; off > 0; off >>= 1) m = fmaxf(m, __shfl_down(m, off, 64));
  __shared__ float wm[4];
  if ((t & 63) == 0) wm[t >> 6] = m;
  __syncthreads();
  if (t == 0) {
    float mm = fmaxf(fmaxf(wm[0], wm[1]), fmaxf(wm[2], wm[3]));
    float dbound = 2.f * sqrtf(mm);       // d <= |xi|+|xj| <= 2*max|x|
    hdrf[2] = 65535.f / dbound;
    hdrf[3] = dbound / 65535.f;
  }
}

// ---------- split fp32 -> (hi, lo) bf16 for error-compensated MFMA ----------
__global__ void k_split(const float* __restrict__ x1, const float* __restrict__ x2,
                        unsigned short* __restrict__ xh, unsigned short* __restrict__ xl) {
  int i = blockIdx.x * blockDim.x + threadIdx.x;
  if (i >= 2 * NN * DF) return;
  const float* x = (i < NN * DF) ? x1 : x2;
  float v = x[i & (NN * DF - 1)];
  unsigned u = __float_as_uint(v);
  unsigned hu = u & 0xffff0000u;
  float hf = __uint_as_float(hu);
  float lf = v - hf;
  unsigned lu = __float_as_uint(lf) & 0xffff0000u;
  xh[i] = (unsigned short)(hu >> 16);
  xl[i] = (unsigned short)(lu >> 16);
}

// ---------- Boruvka init ----------
__global__ void k_binit(int* __restrict__ comp, unsigned long long* __restrict__ compbest,
                        int* __restrict__ mstcnt, int* __restrict__ ncomp) {
  int i = blockIdx.x * blockDim.x + threadIdx.x;
  if (i >= 2 * NN) return;
  comp[i] = i & (NN - 1);
  compbest[i] = ~0ull;
  if ((i & (NN - 1)) == 0) {
    mstcnt[i >> 12] = 0;
    ncomp[i >> 12] = NN;
  }
}

// ---------- distances via split-bf16 MFMA Gram (R2-exact, prefill removed) ----------
// R14: segmin moved into k_hist (which streams Q anyway); k_dist reverts to the
// proven 55us R2 structure (VGPR 116, 4 blocks/CU).
#define SJ 136   // u16 stride for store-stage T: 272 B rows, 16B-aligned
__global__ __launch_bounds__(256) void k_dist(const unsigned short* __restrict__ Xhi,
                                              const unsigned short* __restrict__ Xlo,
                                              const float* __restrict__ sq,
                                              const float* __restrict__ hdrf,
                                              unsigned short* __restrict__ Qbase,
                                              unsigned* __restrict__ caps) {
  int bi = blockIdx.y, bj = blockIdx.x;
  if (bi > bj) return;                       // triangle only
  bool offdiag = (bi != bj);
  int g = blockIdx.z;
  const unsigned short* xh = Xhi + (size_t)g * NN * DF;
  const unsigned short* xl = Xlo + (size_t)g * NN * DF;
  const float* sqg = sq + g * NN;
  unsigned short* Q = Qbase + (size_t)g * NN * NN;
  float qs = hdrf[2];
  int t = threadIdx.x;
  int w = t >> 6, lane = t & 63;
  int m = lane & 15, quad = lane >> 4;
  int iw = (w >> 1) * 64, jw = (w & 1) * 64;   // wave's local tile offsets
  int i0 = bi * 128 + iw;
  int j0 = bj * 128 + jw;

  __shared__ __align__(16) unsigned short SB[128 * SJ];   // staging, then store-stage T

  int baseRow = (w < 2) ? bi * 128 : bj * 128;
  const unsigned short* src = (w == 0 || w == 2) ? xh : xl;
  unsigned short* ldsPiece = &SB[w * 4096];
  int rsub = lane >> 2;                         // 0..15: row within 16-row chunk
  int kpart = (lane & 3) ^ ((lane >> 3) & 3);   // inverse-swizzled k-slot (source side)
  int fr = (quad ^ ((m >> 1) & 3)) << 3;        // read-side swizzle slot

  floatx4 acc[4][4];
#pragma unroll
  for (int ti = 0; ti < 4; ++ti)
#pragma unroll
    for (int tj = 0; tj < 4; ++tj) acc[ti][tj] = (floatx4){0.f, 0.f, 0.f, 0.f};

  for (int s = 0; s < 4; ++s) {
    int kc = s * 32;
    if (s) __syncthreads();                     // previous slab fully consumed
#pragma unroll
    for (int i = 0; i < 8; ++i) {
      const unsigned short* gp =
          src + (size_t)(baseRow + i * 16 + rsub) * DF + kc + kpart * 8;
      gload16(gp, &ldsPiece[i * 512]);
    }
    __syncthreads();
    short8 ah[4], al[4], bh[4], bl[4];
#pragma unroll
    for (int ti = 0; ti < 4; ++ti) {
      int ra = (iw + ti * 16 + m) * 32 + fr;
      int rb = (jw + ti * 16 + m) * 32 + fr;
      ah[ti] = *(const short8*)&SB[ra];
      al[ti] = *(const short8*)&SB[4096 + ra];
      bh[ti] = *(const short8*)&SB[8192 + rb];
      bl[ti] = *(const short8*)&SB[12288 + rb];
    }
#pragma unroll
    for (int ti = 0; ti < 4; ++ti)
#pragma unroll
      for (int tj = 0; tj < 4; ++tj) {
        acc[ti][tj] = __builtin_amdgcn_mfma_f32_16x16x32_bf16(ah[ti], bh[tj], acc[ti][tj], 0, 0, 0);
        acc[ti][tj] = __builtin_amdgcn_mfma_f32_16x16x32_bf16(ah[ti], bl[tj], acc[ti][tj], 0, 0, 0);
        acc[ti][tj] = __builtin_amdgcn_mfma_f32_16x16x32_bf16(al[ti], bh[tj], acc[ti][tj], 0, 0, 0);
      }
  }

  // C/D layout: col = lane&15 (j), row = quad*4 + reg (i)
  float sqj[4];
#pragma unroll
  for (int tj = 0; tj < 4; ++tj) sqj[tj] = sqg[j0 + tj * 16 + m];
  float mx = 0.f;
  ushort4_t qv[4][4];
#pragma unroll
  for (int ti = 0; ti < 4; ++ti) {
    int ib = i0 + ti * 16 + quad * 4;
    float sqiv[4];
#pragma unroll
    for (int r = 0; r < 4; ++r) sqiv[r] = sqg[ib + r];
#pragma unroll
    for (int tj = 0; tj < 4; ++tj) {
#pragma unroll
      for (int r = 0; r < 4; ++r) {
        float d2 = sqiv[r] + sqj[tj] - 2.f * acc[ti][tj][r];
        d2 = fmaxf(d2, 0.f);
        float d = (d2 > 1e-12f) ? sqrtf(d2) : 0.f;
        mx = fmaxf(mx, d);
        unsigned q = (unsigned)(d * qs + 0.5f);
        if (q > 65535u) q = 65535u;
        qv[ti][tj][r] = (unsigned short)q;
      }
    }
  }

  __syncthreads();   // staging reads done in all waves; SB now reusable as T
  unsigned short* T = SB;
  int sub = t >> 4, l16 = t & 15;

  // ---- phase A: transposed layout T[jl][il], dump lower/transposed half ----
#pragma unroll
  for (int ti = 0; ti < 4; ++ti) {
    int il = iw + ti * 16 + quad * 4;
#pragma unroll
    for (int tj = 0; tj < 4; ++tj) {
      int jl = jw + tj * 16 + m;
      *(ushort4_t*)&T[jl * SJ + il] = qv[ti][tj];
    }
  }
  __syncthreads();
#pragma unroll
  for (int k = 0; k < 8; ++k) {
    int jl = k * 16 + sub;
    int4_t v = *(const int4_t*)&T[jl * SJ + l16 * 8];
    *(int4_t*)&Q[(size_t)(bj * 128 + jl) * NN + bi * 128 + l16 * 8] = v;
  }

  // ---- phase B (off-diagonal only): normal layout T[il][jl], dump upper half ----
  if (offdiag) {
    __syncthreads();
#pragma unroll
    for (int ti = 0; ti < 4; ++ti) {
      int il = iw + ti * 16 + quad * 4;
#pragma unroll
      for (int tj = 0; tj < 4; ++tj) {
        int jl = jw + tj * 16 + m;
#pragma unroll
        for (int r = 0; r < 4; ++r) T[(il + r) * SJ + jl] = qv[ti][tj][r];
      }
    }
    __syncthreads();
#pragma unroll
    for (int k = 0; k < 8; ++k) {
      int il = k * 16 + sub;
      int4_t v = *(const int4_t*)&T[il * SJ + l16 * 8];
      *(int4_t*)&Q[(size_t)(bi * 128 + il) * NN + bj * 128 + l16 * 8] = v;
    }
  }

  for (int off = 32; off > 0; off >>= 1) mx = fmaxf(mx, __shfl_down(mx, off, 64));
  __shared__ float wmax[4];
  if (lane == 0) wmax[w] = mx;
  __syncthreads();
  if (t == 0) {
    float mm = fmaxf(fmaxf(wmax[0], wmax[1]), fmaxf(wmax[2], wmax[3]));
    atomicMax(&caps[g], __float_as_uint(mm));
  }
}

// ---------- histogram + segmin: full-row streaming (R14) ----------
// Block b (graph g, slab s) handles rows s + k*NSLAB (k=0..15), reading FULL rows.
// Per row: hist-bin cols > row (same counts as before); per-128-col segment min
// keys (q<<7)|col_local, col!=row excluded, reduced wave-locally (16-lane groups
// own one segment's 16 chunks) -> segmin[row][32]. Identical values to R11's
// k_dist prefill; frees k_dist of the ~29us prefill cost.
__global__ __launch_bounds__(256) void k_hist(const unsigned short* __restrict__ Qbase,
                                              const unsigned* __restrict__ caps,
                                              const float* __restrict__ hdrf,
                                              unsigned* __restrict__ Hs,
                                              unsigned* __restrict__ segmin_base) {
  __shared__ unsigned h[NBINS];
  int t = threadIdx.x;
  for (int i = t; i < NBINS; i += 256) h[i] = 0;
  int b = blockIdx.x;
  int g = b >> 8, s = b & (NSLAB - 1);
  const unsigned short* Q = Qbase + (size_t)g * NN * NN;
  unsigned* smg = segmin_base + (size_t)g * NN * 32;
  float cap = __uint_as_float(caps[g]);
  float capmax = fmaxf(__uint_as_float(caps[0]), __uint_as_float(caps[1]));
  float scale = (float)NBINS / capmax;
  float qinv = hdrf[3];
  int w = t >> 6, lane = t & 63;
  __syncthreads();
  for (int k = 0; k < 16; ++k) {
    int row = s + k * NSLAB;
    const unsigned short* rp = Q + (size_t)row * NN;
#pragma unroll
    for (int pp = 0; pp < 2; ++pp) {
      int c = pp * 256 + w * 64 + lane;        // chunk 0..511; seg = c>>4 uniform per 16-lane group
      int col0 = c * 8;
      ushort8_t v8 = *(const ushort8_t*)&rp[col0];
      unsigned kmin = 0xffffffffu;
#pragma unroll
      for (int u = 0; u < 8; ++u) {
        int col = col0 + u;
        unsigned q = (unsigned short)v8[u];
        if (col > row)
          atomicAdd(&h[bin_of(cap - (float)q * qinv, scale)], 1u);
        if (col != row) {
          unsigned key = (q << 7) | (unsigned)(col & 127);
          if (key < kmin) kmin = key;
        }
      }
#pragma unroll
      for (int off = 1; off < 16; off <<= 1) {
        unsigned o = (unsigned)__shfl_xor((int)kmin, off, 16);
        if (o < kmin) kmin = o;
      }
      if ((lane & 15) == 0) smg[(size_t)row * 32 + (c >> 4)] = kmin;
    }
  }
  __syncthreads();
  unsigned* slab = Hs + (size_t)b * NBINS;
  for (int i = t; i < NBINS; i += 256) slab[i] = h[i];
}

// ---------- Boruvka step 1: segment-table min edge (R11-proven, verbatim) ----------
__global__ __launch_bounds__(256) void k_minedge(const unsigned short* __restrict__ Qbase,
                                                 const unsigned* __restrict__ segmin_base,
                                                 const int* __restrict__ comp_base,
                                                 unsigned long long* __restrict__ compbest_base,
                                                 const int* __restrict__ ncomp) {
  int g = blockIdx.y;
  if (ncomp[g] == 1) return;
  int w = threadIdx.x >> 6, lane = threadIdx.x & 63;
  int v = blockIdx.x * 4 + w;
  const int* comp = comp_base + g * NN;
  unsigned long long* cbest = compbest_base + (size_t)g * NN;
  int cv = comp[v];
  const unsigned* sm = segmin_base + ((size_t)g * NN + (size_t)v) * 32;

  unsigned key28 = 0xffffffffu;   // (q<<12)|col
  bool incomp = false;
  if (lane < 32) {
    unsigned k23 = sm[lane];
    unsigned q = k23 >> 7, cl = k23 & 127u;
    unsigned col = (unsigned)lane * 128u + cl;
    key28 = (q << 12) | col;
    incomp = (comp[col] == cv);
  }
  unsigned a = (lane < 32 && !incomp) ? key28 : 0xffffffffu;
#pragma unroll
  for (int off = 1; off < 64; off <<= 1) {
    unsigned o = (unsigned)__shfl_xor((int)a, off, 64);
    if (o < a) a = o;
  }
  unsigned best = a;   // candidate from out-of-comp argmins (all lanes agree)

  // segments that could still hide the true min
  unsigned long long flags = __ballot(lane < 32 && incomp && key28 < best);
  if (flags) {
    const unsigned short* row = Qbase + ((size_t)g * NN + (size_t)v) * NN;
    while (flags) {
      int s = (int)(__ffsll((long long)flags) - 1);
      flags &= flags - 1;
      int j = s * 128 + (lane << 1);
      unsigned pq = *(const unsigned*)&row[j];          // 2 u16 distances
      ivec2 cj = *(const ivec2*)&comp[j];
      unsigned k1 = (cj[0] != cv) ? ((pq & 0xffffu) << 12) | (unsigned)j : 0xffffffffu;
      unsigned k2 = (cj[1] != cv) ? ((pq >> 16) << 12) | (unsigned)(j + 1) : 0xffffffffu;
      unsigned kk = k1 < k2 ? k1 : k2;
#pragma unroll
      for (int off = 1; off < 64; off <<= 1) {
        unsigned o = (unsigned)__shfl_xor((int)kk, off, 64);
        if (o < kk) kk = o;
      }
      if (kk < best) best = kk;
    }
  }
  if (lane == 0 && best != 0xffffffffu) {
    unsigned long long b64 = ((unsigned long long)(best >> 12) << 24) |
                             ((unsigned long long)v << 12) | (best & 0xfffu);
    atomicMin(&cbest[cv], b64);
  }
}

// ---------- Boruvka step 2: hook/contract (1024 threads, R9-proven, verbatim) ----------
__global__ __launch_bounds__(1024) void k_hook(unsigned long long* __restrict__ compbest_base,
                                               int* __restrict__ comp_base,
                                               const float* __restrict__ hdrf,
                                               float* __restrict__ mstw_base,
                                               int* __restrict__ mstcnt,
                                               int* __restrict__ ncomp) {
  int g = blockIdx.x;
  if (ncomp[g] == 1) return;
  unsigned long long* cb = compbest_base + (size_t)g * NN;
  int* comp = comp_base + g * NN;
  float* mstw = mstw_base + g * (NN - 1);
  float qinv = hdrf[3];
  __shared__ int par[NN];
  __shared__ unsigned char live[NN];
  __shared__ int newcnt;
  int t = threadIdx.x;
  if (t == 0) newcnt = 0;
  for (int c = t; c < NN; c += 1024) {
    unsigned long long key = cb[c];
    bool a = (key != ~0ull);
    live[c] = a ? 1 : 0;
    int p = c;
    if (a) {
      int j = (int)(key & 0xfffull);
      p = comp[j];
    }
    par[c] = p;
  }
  __syncthreads();
  // break 2-cycles: smaller label becomes root (each thread writes own slots)
  for (int c = t; c < NN; c += 1024) {
    int p = par[c];
    if (p != c && par[p] == c && c < p) par[c] = c;
  }
  __syncthreads();
  // emit one MST weight per hooked component (dequantized)
  for (int c = t; c < NN; c += 1024) {
    if (live[c] && par[c] != c) {
      float w = (float)((unsigned)(cb[c] >> 24)) * qinv;
      int slot = atomicAdd(&mstcnt[g], 1);
      mstw[slot] = w;
    }
  }
  __syncthreads();
  // pointer jumping until stable (hook forests are shallow: typ 2-4 iters)
  for (;;) {
    int np[NN / 1024];
    bool ch = false;
    int k = 0;
    for (int c = t; c < NN; c += 1024, ++k) {
      int p = par[c];
      int pp = par[p];
      np[k] = pp;
      if (pp != p) ch = true;
    }
    __syncthreads();
    k = 0;
    for (int c = t; c < NN; c += 1024, ++k) par[c] = np[k];
    if (!__syncthreads_or(ch)) break;
  }
  // count roots
  int cnt = 0;
  for (int c = t; c < NN; c += 1024)
    if (live[c] && par[c] == c) cnt++;
  for (int off = 32; off > 0; off >>= 1) cnt += __shfl_down(cnt, off, 64);
  if ((t & 63) == 0 && cnt) atomicAdd(&newcnt, cnt);
  // relabel vertices + reset compbest
  for (int v = t; v < NN; v += 1024) comp[v] = par[comp[v]];
  for (int c = t; c < NN; c += 1024) cb[c] = ~0ull;
  __syncthreads();
  if (t == 0) ncomp[g] = newcnt;
}

// ---------- move tree edges to persistence 0 (slab 0; same dequant grid => exact) ----------
__global__ void k_treefix(const float* __restrict__ twbase, const unsigned* __restrict__ caps,
                          unsigned* __restrict__ Hs) {
  int g = blockIdx.y;
  unsigned* hist = Hs + (size_t)(g * NSLAB) * NBINS;
  float cap = __uint_as_float(caps[g]);
  float capmax = fmaxf(__uint_as_float(caps[0]), __uint_as_float(caps[1]));
  float scale = (float)NBINS / capmax;
  int idx = blockIdx.x * blockDim.x + threadIdx.x;
  if (idx < NN - 1) {
    float w = twbase[g * (NN - 1) + idx];
    atomicSub(&hist[bin_of(cap - w, scale)], 1u);  // may wrap; per-bin total stays >= 0
    atomicAdd(&hist[0], 1u);
  }
}

// ---------- merge 256 slabs per graph -> Hm[2][NBINS] ----------
__global__ __launch_bounds__(256) void k_merge(const unsigned* __restrict__ Hs,
                                               unsigned* __restrict__ Hm) {
  int id = blockIdx.x * 256 + threadIdx.x;  // 0 .. 2*NBINS-1
  int g = id >> 14;
  int i = id & (NBINS - 1);
  const unsigned* base = Hs + (size_t)(g * NSLAB) * NBINS + i;
  unsigned sum = 0;
  for (int s = 0; s < NSLAB; ++s) sum += base[(size_t)s * NBINS];
  Hm[id] = sum;
}

// ---------- W1: single block computes sum |running prefix| * dt ----------
__global__ __launch_bounds__(256) void k_w1(const unsigned* __restrict__ Hm,
                                            const unsigned* __restrict__ caps,
                                            float* __restrict__ out) {
  int t = threadIdx.x;
  const int PB = NBINS / 256;  // 64 bins per thread
  int base = t * PB;
  long long tsum = 0;
  for (int i = 0; i < PB; ++i)
    tsum += (long long)(int)(Hm[base + i] - Hm[NBINS + base + i]);
  int lane = t & 63, wid = t >> 6;
  long long incl = tsum;
  for (int off = 1; off < 64; off <<= 1) {
    long long o = __shfl_up(incl, off, 64);
    if (lane >= off) incl += o;
  }
  __shared__ long long wtot[4];
  if (lane == 63) wtot[wid] = incl;
  __syncthreads();
  long long run = incl - tsum;
  for (int w = 0; w < wid; ++w) run += wtot[w];
  unsigned long long local = 0;
  for (int i = 0; i < PB; ++i) {
    run += (long long)(int)(Hm[base + i] - Hm[NBINS + base + i]);
    local += (unsigned long long)(run < 0 ? -run : run);
  }
  for (int off = 32; off > 0; off >>= 1) local += __shfl_down(local, off, 64);
  __shared__ unsigned long long wl[4];
  if (lane == 0) wl[wid] = local;
  __syncthreads();
  if (t == 0) {
    float capmax = fmaxf(__uint_as_float(caps[0]), __uint_as_float(caps[1]));
    double dt = (double)capmax / (double)NBINS;
    out[0] = (float)((double)(wl[0] + wl[1] + wl[2] + wl[3]) * dt);
  }
}

__global__ void k_fail(float* out) { out[0] = -1234567.0f; }

extern "C" void kernel_launch(void* const* d_in, const int* in_sizes, int n_in,
                              void* d_out, int out_size, void* d_ws, size_t ws_size,
                              hipStream_t stream) {
  const float* x1 = (const float*)d_in[0];
  const float* x2 = (const float*)d_in[2];
  float* out = (float*)d_out;
  char* ws = (char*)d_ws;

  const size_t offQ = 0;                                        // u16 D: 64 MiB
  const size_t offS = 2ull * NN * NN * 2ull;                    // slabs: 32 MiB
  const size_t offHm = offS + 2ull * NSLAB * NBINS * 4ull;      // 128 KiB merged hist
  const size_t offHdr = offHm + 2ull * NBINS * 4ull;            // caps+qscale+qinv
  const size_t offSq = offHdr + 64;
  const size_t offTw = offSq + 2ull * NN * 4ull;
  const size_t offCb = (offTw + 2ull * (NN - 1) * 4ull + 7ull) & ~7ull;
  const size_t offSeg = offCb + 2ull * NN * 8ull;               // segmin: 1 MiB
  const size_t offCp = offSeg + 2ull * NN * 32ull * 4ull;
  const size_t offMeta = offCp + 2ull * NN * 4ull;              // mstcnt[2], ncomp[2]
  const size_t needed = offMeta + 64;
  if (ws_size < needed) {
    hipLaunchKernelGGL(k_fail, dim3(1), dim3(1), 0, stream, out);
    return;
  }

  unsigned short* Qbase = (unsigned short*)(ws + offQ);
  unsigned* Hs = (unsigned*)(ws + offS);
  // Xhi/Xlo (4 MiB) transiently live in the slab region (dead before k_hist writes it)
  unsigned short* Xhi = (unsigned short*)(ws + offS);
  unsigned short* Xlo = (unsigned short*)(ws + offS + 2ull * NN * DF * 2ull);
  unsigned* Hm = (unsigned*)(ws + offHm);
  unsigned* caps = (unsigned*)(ws + offHdr);
  float* hdrf = (float*)(ws + offHdr);
  float* sq = (float*)(ws + offSq);
  float* tw = (float*)(ws + offTw);
  unsigned long long* compbest = (unsigned long long*)(ws + offCb);
  unsigned* segmin = (unsigned*)(ws + offSeg);
  int* comp = (int*)(ws + offCp);
  int* mstcnt = (int*)(ws + offMeta);
  int* ncomp = (int*)(ws + offMeta + 8);

  // zero header (caps; qscale/qinv overwritten by k_bound)
  hipMemsetAsync(ws + offHdr, 0, 64, stream);

  hipLaunchKernelGGL(k_rownorm, dim3((2 * NN + 255) / 256), dim3(256), 0, stream, x1, x2, sq);
  hipLaunchKernelGGL(k_bound, dim3(1), dim3(256), 0, stream, sq, hdrf);
  hipLaunchKernelGGL(k_split, dim3((2 * NN * DF + 255) / 256), dim3(256), 0, stream,
                     x1, x2, Xhi, Xlo);
  hipLaunchKernelGGL(k_binit, dim3((2 * NN + 255) / 256), dim3(256), 0, stream,
                     comp, compbest, mstcnt, ncomp);
  hipLaunchKernelGGL(k_dist, dim3(NN / 128, NN / 128, 2), dim3(256), 0, stream,
                     Xhi, Xlo, sq, hdrf, Qbase, caps);
  // k_hist BEFORE Boruvka: streams Q once for the histogram AND the segmin table
  hipLaunchKernelGGL(k_hist, dim3(2 * NSLAB), dim3(256), 0, stream,
                     Qbase, caps, hdrf, Hs, segmin);
  for (int r = 0; r < BORUVKA_ROUNDS; ++r) {
    hipLaunchKernelGGL(k_minedge, dim3(NN / 4, 2), dim3(256), 0, stream,
                       Qbase, segmin, comp, compbest, ncomp);
    hipLaunchKernelGGL(k_hook, dim3(2), dim3(1024), 0, stream,
                       compbest, comp, hdrf, tw, mstcnt, ncomp);
  }
  hipLaunchKernelGGL(k_treefix, dim3(16, 2), dim3(256), 0, stream, tw, caps, Hs);
  hipLaunchKernelGGL(k_merge, dim3(2 * NBINS / 256), dim3(256), 0, stream, Hs, Hm);
  hipLaunchKernelGGL(k_w1, dim3(1), dim3(256), 0, stream, Hm, caps, out);
}

// Round 16
// 330.651 us; speedup vs baseline: 11.5265x; 1.0248x over previous
//
#include <hip/hip_runtime.h>
#include <stdint.h>

#define NN 4096
#define DF 128
#define NBINS 16384          // fine bins; fits LDS (64 KiB u32)
#define NSLAB 256            // histogram slabs per graph
#define BORUVKA_ROUNDS 12

typedef __attribute__((ext_vector_type(8))) short short8;
typedef __attribute__((ext_vector_type(4))) float floatx4;
typedef __attribute__((ext_vector_type(4))) unsigned short ushort4_t;
typedef __attribute__((ext_vector_type(8))) unsigned short ushort8_t;
typedef __attribute__((ext_vector_type(4))) int int4_t;
typedef __attribute__((ext_vector_type(2))) int ivec2;

// ---------- helpers ----------
__device__ __forceinline__ unsigned bin_of(float v, float scale) {
  if (v < 0.f) v = 0.f;
  unsigned b = (unsigned)(v * scale);
  return b >= (unsigned)NBINS ? (unsigned)(NBINS - 1) : b;
}

// async global->LDS, 16B per lane; dest = wave-uniform base + lane*16
__device__ __forceinline__ void gload16(const unsigned short* g, unsigned short* l) {
  __builtin_amdgcn_global_load_lds(
      (const __attribute__((address_space(1))) void*)g,
      (__attribute__((address_space(3))) void*)l, 16, 0, 0);
}

// ---------- row squared norms for both graphs (fp32, serial order preserved) ----------
__global__ void k_rownorm(const float* __restrict__ x1, const float* __restrict__ x2,
                          float* __restrict__ sq) {
  int i = blockIdx.x * blockDim.x + threadIdx.x;
  if (i >= 2 * NN) return;
  const float* x = (i < NN) ? x1 : x2;
  int r = i & (NN - 1);
  const float* row = x + (size_t)r * DF;
  float s = 0.f;
  for (int k = 0; k < DF; ++k) s += row[k] * row[k];
  sq[i] = s;
}

// ---------- distance upper bound -> u16 quantization scales ----------
// hdrf: [0..1]=caps(u32), [2]=qscale, [3]=qinv
__global__ __launch_bounds__(256) void k_bound(const float* __restrict__ sq,
                                               float* __restrict__ hdrf) {
  int t = threadIdx.x;
  float m = 0.f;
  for (int i = t; i < 2 * NN; i += 256) m = fmaxf(m, sq[i]);
  for (int off = 32; off > 0; off >>= 1) m = fmaxf(m, __shfl_down(m, off, 64));
  __shared__ float wm[4];
  if ((t & 63) == 0) wm[t >> 6] = m;
  __syncthreads();
  if (t == 0) {
    float mm = fmaxf(fmaxf(wm[0], wm[1]), fmaxf(wm[2], wm[3]));
    float dbound = 2.f * sqrtf(mm);       // d <= |xi|+|xj| <= 2*max|x|
    hdrf[2] = 65535.f / dbound;
    hdrf[3] = dbound / 65535.f;
  }
}

// ---------- split fp32 -> (hi, lo) bf16 + fused Boruvka/header init (R15/R16) ----------
// Threads i < 2*NN also run the old k_binit; threads 0,1 zero caps (replaces the
// hipMemsetAsync). k_bound writes hdrf[2..3] earlier — disjoint words, safe.
// R16 = R15 resubmitted verbatim after an infra-side container failure
// (third occurrence; R5->R6 and R10->R11 precedent: resubmit passed).
__global__ void k_split(const float* __restrict__ x1, const float* __restrict__ x2,
                        unsigned short* __restrict__ xh, unsigned short* __restrict__ xl,
                        int* __restrict__ comp, unsigned long long* __restrict__ compbest,
                        int* __restrict__ mstcnt, int* __restrict__ ncomp,
                        unsigned* __restrict__ caps) {
  int i = blockIdx.x * blockDim.x + threadIdx.x;
  if (i >= 2 * NN * DF) return;
  if (i < 2 * NN) {
    comp[i] = i & (NN - 1);
    compbest[i] = ~0ull;
    if ((i & (NN - 1)) == 0) {
      mstcnt[i >> 12] = 0;
      ncomp[i >> 12] = NN;
    }
    if (i < 2) caps[i] = 0u;
  }
  const float* x = (i < NN * DF) ? x1 : x2;
  float v = x[i & (NN * DF - 1)];
  unsigned u = __float_as_uint(v);
  unsigned hu = u & 0xffff0000u;
  float hf = __uint_as_float(hu);
  float lf = v - hf;
  unsigned lu = __float_as_uint(lf) & 0xffff0000u;
  xh[i] = (unsigned short)(hu >> 16);
  xl[i] = (unsigned short)(lu >> 16);
}

// ---------- distances via split-bf16 MFMA Gram (R2-exact, R14-proven) ----------
#define SJ 136   // u16 stride for store-stage T: 272 B rows, 16B-aligned
__global__ __launch_bounds__(256) void k_dist(const unsigned short* __restrict__ Xhi,
                                              const unsigned short* __restrict__ Xlo,
                                              const float* __restrict__ sq,
                                              const float* __restrict__ hdrf,
                                              unsigned short* __restrict__ Qbase,
                                              unsigned* __restrict__ caps) {
  int bi = blockIdx.y, bj = blockIdx.x;
  if (bi > bj) return;                       // triangle only
  bool offdiag = (bi != bj);
  int g = blockIdx.z;
  const unsigned short* xh = Xhi + (size_t)g * NN * DF;
  const unsigned short* xl = Xlo + (size_t)g * NN * DF;
  const float* sqg = sq + g * NN;
  unsigned short* Q = Qbase + (size_t)g * NN * NN;
  float qs = hdrf[2];
  int t = threadIdx.x;
  int w = t >> 6, lane = t & 63;
  int m = lane & 15, quad = lane >> 4;
  int iw = (w >> 1) * 64, jw = (w & 1) * 64;   // wave's local tile offsets
  int i0 = bi * 128 + iw;
  int j0 = bj * 128 + jw;

  __shared__ __align__(16) unsigned short SB[128 * SJ];   // staging, then store-stage T

  int baseRow = (w < 2) ? bi * 128 : bj * 128;
  const unsigned short* src = (w == 0 || w == 2) ? xh : xl;
  unsigned short* ldsPiece = &SB[w * 4096];
  int rsub = lane >> 2;                         // 0..15: row within 16-row chunk
  int kpart = (lane & 3) ^ ((lane >> 3) & 3);   // inverse-swizzled k-slot (source side)
  int fr = (quad ^ ((m >> 1) & 3)) << 3;        // read-side swizzle slot

  floatx4 acc[4][4];
#pragma unroll
  for (int ti = 0; ti < 4; ++ti)
#pragma unroll
    for (int tj = 0; tj < 4; ++tj) acc[ti][tj] = (floatx4){0.f, 0.f, 0.f, 0.f};

  for (int s = 0; s < 4; ++s) {
    int kc = s * 32;
    if (s) __syncthreads();                     // previous slab fully consumed
#pragma unroll
    for (int i = 0; i < 8; ++i) {
      const unsigned short* gp =
          src + (size_t)(baseRow + i * 16 + rsub) * DF + kc + kpart * 8;
      gload16(gp, &ldsPiece[i * 512]);
    }
    __syncthreads();
    short8 ah[4], al[4], bh[4], bl[4];
#pragma unroll
    for (int ti = 0; ti < 4; ++ti) {
      int ra = (iw + ti * 16 + m) * 32 + fr;
      int rb = (jw + ti * 16 + m) * 32 + fr;
      ah[ti] = *(const short8*)&SB[ra];
      al[ti] = *(const short8*)&SB[4096 + ra];
      bh[ti] = *(const short8*)&SB[8192 + rb];
      bl[ti] = *(const short8*)&SB[12288 + rb];
    }
#pragma unroll
    for (int ti = 0; ti < 4; ++ti)
#pragma unroll
      for (int tj = 0; tj < 4; ++tj) {
        acc[ti][tj] = __builtin_amdgcn_mfma_f32_16x16x32_bf16(ah[ti], bh[tj], acc[ti][tj], 0, 0, 0);
        acc[ti][tj] = __builtin_amdgcn_mfma_f32_16x16x32_bf16(ah[ti], bl[tj], acc[ti][tj], 0, 0, 0);
        acc[ti][tj] = __builtin_amdgcn_mfma_f32_16x16x32_bf16(al[ti], bh[tj], acc[ti][tj], 0, 0, 0);
      }
  }

  // C/D layout: col = lane&15 (j), row = quad*4 + reg (i)
  float sqj[4];
#pragma unroll
  for (int tj = 0; tj < 4; ++tj) sqj[tj] = sqg[j0 + tj * 16 + m];
  float mx = 0.f;
  ushort4_t qv[4][4];
#pragma unroll
  for (int ti = 0; ti < 4; ++ti) {
    int ib = i0 + ti * 16 + quad * 4;
    float sqiv[4];
#pragma unroll
    for (int r = 0; r < 4; ++r) sqiv[r] = sqg[ib + r];
#pragma unroll
    for (int tj = 0; tj < 4; ++tj) {
#pragma unroll
      for (int r = 0; r < 4; ++r) {
        float d2 = sqiv[r] + sqj[tj] - 2.f * acc[ti][tj][r];
        d2 = fmaxf(d2, 0.f);
        float d = (d2 > 1e-12f) ? sqrtf(d2) : 0.f;
        mx = fmaxf(mx, d);
        unsigned q = (unsigned)(d * qs + 0.5f);
        if (q > 65535u) q = 65535u;
        qv[ti][tj][r] = (unsigned short)q;
      }
    }
  }

  __syncthreads();   // staging reads done in all waves; SB now reusable as T
  unsigned short* T = SB;
  int sub = t >> 4, l16 = t & 15;

  // ---- phase A: transposed layout T[jl][il], dump lower/transposed half ----
#pragma unroll
  for (int ti = 0; ti < 4; ++ti) {
    int il = iw + ti * 16 + quad * 4;
#pragma unroll
    for (int tj = 0; tj < 4; ++tj) {
      int jl = jw + tj * 16 + m;
      *(ushort4_t*)&T[jl * SJ + il] = qv[ti][tj];
    }
  }
  __syncthreads();
#pragma unroll
  for (int k = 0; k < 8; ++k) {
    int jl = k * 16 + sub;
    int4_t v = *(const int4_t*)&T[jl * SJ + l16 * 8];
    *(int4_t*)&Q[(size_t)(bj * 128 + jl) * NN + bi * 128 + l16 * 8] = v;
  }

  // ---- phase B (off-diagonal only): normal layout T[il][jl], dump upper half ----
  if (offdiag) {
    __syncthreads();
#pragma unroll
    for (int ti = 0; ti < 4; ++ti) {
      int il = iw + ti * 16 + quad * 4;
#pragma unroll
      for (int tj = 0; tj < 4; ++tj) {
        int jl = jw + tj * 16 + m;
#pragma unroll
        for (int r = 0; r < 4; ++r) T[(il + r) * SJ + jl] = qv[ti][tj][r];
      }
    }
    __syncthreads();
#pragma unroll
    for (int k = 0; k < 8; ++k) {
      int il = k * 16 + sub;
      int4_t v = *(const int4_t*)&T[il * SJ + l16 * 8];
      *(int4_t*)&Q[(size_t)(bi * 128 + il) * NN + bj * 128 + l16 * 8] = v;
    }
  }

  for (int off = 32; off > 0; off >>= 1) mx = fmaxf(mx, __shfl_down(mx, off, 64));
  __shared__ float wmax[4];
  if (lane == 0) wmax[w] = mx;
  __syncthreads();
  if (t == 0) {
    float mm = fmaxf(fmaxf(wmax[0], wmax[1]), fmaxf(wmax[2], wmax[3]));
    atomicMax(&caps[g], __float_as_uint(mm));
  }
}

// ---------- histogram + segmin: full-row streaming (R14-proven) ----------
__global__ __launch_bounds__(256) void k_hist(const unsigned short* __restrict__ Qbase,
                                              const unsigned* __restrict__ caps,
                                              const float* __restrict__ hdrf,
                                              unsigned* __restrict__ Hs,
                                              unsigned* __restrict__ segmin_base) {
  __shared__ unsigned h[NBINS];
  int t = threadIdx.x;
  for (int i = t; i < NBINS; i += 256) h[i] = 0;
  int b = blockIdx.x;
  int g = b >> 8, s = b & (NSLAB - 1);
  const unsigned short* Q = Qbase + (size_t)g * NN * NN;
  unsigned* smg = segmin_base + (size_t)g * NN * 32;
  float cap = __uint_as_float(caps[g]);
  float capmax = fmaxf(__uint_as_float(caps[0]), __uint_as_float(caps[1]));
  float scale = (float)NBINS / capmax;
  float qinv = hdrf[3];
  int w = t >> 6, lane = t & 63;
  __syncthreads();
  for (int k = 0; k < 16; ++k) {
    int row = s + k * NSLAB;
    const unsigned short* rp = Q + (size_t)row * NN;
#pragma unroll
    for (int pp = 0; pp < 2; ++pp) {
      int c = pp * 256 + w * 64 + lane;        // chunk 0..511; seg = c>>4 uniform per 16-lane group
      int col0 = c * 8;
      ushort8_t v8 = *(const ushort8_t*)&rp[col0];
      unsigned kmin = 0xffffffffu;
#pragma unroll
      for (int u = 0; u < 8; ++u) {
        int col = col0 + u;
        unsigned q = (unsigned short)v8[u];
        if (col > row)
          atomicAdd(&h[bin_of(cap - (float)q * qinv, scale)], 1u);
        if (col != row) {
          unsigned key = (q << 7) | (unsigned)(col & 127);
          if (key < kmin) kmin = key;
        }
      }
#pragma unroll
      for (int off = 1; off < 16; off <<= 1) {
        unsigned o = (unsigned)__shfl_xor((int)kmin, off, 16);
        if (o < kmin) kmin = o;
      }
      if ((lane & 15) == 0) smg[(size_t)row * 32 + (c >> 4)] = kmin;
    }
  }
  __syncthreads();
  unsigned* slab = Hs + (size_t)b * NBINS;
  for (int i = t; i < NBINS; i += 256) slab[i] = h[i];
}

// ---------- Boruvka step 1: segment-table min edge (R11 logic, 16 waves/block) ----------
__global__ __launch_bounds__(1024) void k_minedge(const unsigned short* __restrict__ Qbase,
                                                  const unsigned* __restrict__ segmin_base,
                                                  const int* __restrict__ comp_base,
                                                  unsigned long long* __restrict__ compbest_base,
                                                  const int* __restrict__ ncomp) {
  int g = blockIdx.y;
  if (ncomp[g] == 1) return;
  int w = threadIdx.x >> 6, lane = threadIdx.x & 63;
  int v = blockIdx.x * 16 + w;
  const int* comp = comp_base + g * NN;
  unsigned long long* cbest = compbest_base + (size_t)g * NN;
  int cv = comp[v];
  const unsigned* sm = segmin_base + ((size_t)g * NN + (size_t)v) * 32;

  unsigned key28 = 0xffffffffu;   // (q<<12)|col
  bool incomp = false;
  if (lane < 32) {
    unsigned k23 = sm[lane];
    unsigned q = k23 >> 7, cl = k23 & 127u;
    unsigned col = (unsigned)lane * 128u + cl;
    key28 = (q << 12) | col;
    incomp = (comp[col] == cv);
  }
  unsigned a = (lane < 32 && !incomp) ? key28 : 0xffffffffu;
#pragma unroll
  for (int off = 1; off < 64; off <<= 1) {
    unsigned o = (unsigned)__shfl_xor((int)a, off, 64);
    if (o < a) a = o;
  }
  unsigned best = a;   // candidate from out-of-comp argmins (all lanes agree)

  // segments that could still hide the true min
  unsigned long long flags = __ballot(lane < 32 && incomp && key28 < best);
  if (flags) {
    const unsigned short* row = Qbase + ((size_t)g * NN + (size_t)v) * NN;
    while (flags) {
      int s = (int)(__ffsll((long long)flags) - 1);
      flags &= flags - 1;
      int j = s * 128 + (lane << 1);
      unsigned pq = *(const unsigned*)&row[j];          // 2 u16 distances
      ivec2 cj = *(const ivec2*)&comp[j];
      unsigned k1 = (cj[0] != cv) ? ((pq & 0xffffu) << 12) | (unsigned)j : 0xffffffffu;
      unsigned k2 = (cj[1] != cv) ? ((pq >> 16) << 12) | (unsigned)(j + 1) : 0xffffffffu;
      unsigned kk = k1 < k2 ? k1 : k2;
#pragma unroll
      for (int off = 1; off < 64; off <<= 1) {
        unsigned o = (unsigned)__shfl_xor((int)kk, off, 64);
        if (o < kk) kk = o;
      }
      if (kk < best) best = kk;
    }
  }
  if (lane == 0 && best != 0xffffffffu) {
    unsigned long long b64 = ((unsigned long long)(best >> 12) << 24) |
                             ((unsigned long long)v << 12) | (best & 0xfffu);
    atomicMin(&cbest[cv], b64);
  }
}

// ---------- Boruvka step 2: hook/contract (1024 threads, R9-proven, verbatim) ----------
__global__ __launch_bounds__(1024) void k_hook(unsigned long long* __restrict__ compbest_base,
                                               int* __restrict__ comp_base,
                                               const float* __restrict__ hdrf,
                                               float* __restrict__ mstw_base,
                                               int* __restrict__ mstcnt,
                                               int* __restrict__ ncomp) {
  int g = blockIdx.x;
  if (ncomp[g] == 1) return;
  unsigned long long* cb = compbest_base + (size_t)g * NN;
  int* comp = comp_base + g * NN;
  float* mstw = mstw_base + g * (NN - 1);
  float qinv = hdrf[3];
  __shared__ int par[NN];
  __shared__ unsigned char live[NN];
  __shared__ int newcnt;
  int t = threadIdx.x;
  if (t == 0) newcnt = 0;
  for (int c = t; c < NN; c += 1024) {
    unsigned long long key = cb[c];
    bool a = (key != ~0ull);
    live[c] = a ? 1 : 0;
    int p = c;
    if (a) {
      int j = (int)(key & 0xfffull);
      p = comp[j];
    }
    par[c] = p;
  }
  __syncthreads();
  // break 2-cycles: smaller label becomes root (each thread writes own slots)
  for (int c = t; c < NN; c += 1024) {
    int p = par[c];
    if (p != c && par[p] == c && c < p) par[c] = c;
  }
  __syncthreads();
  // emit one MST weight per hooked component (dequantized)
  for (int c = t; c < NN; c += 1024) {
    if (live[c] && par[c] != c) {
      float w = (float)((unsigned)(cb[c] >> 24)) * qinv;
      int slot = atomicAdd(&mstcnt[g], 1);
      mstw[slot] = w;
    }
  }
  __syncthreads();
  // pointer jumping until stable (hook forests are shallow: typ 2-4 iters)
  for (;;) {
    int np[NN / 1024];
    bool ch = false;
    int k = 0;
    for (int c = t; c < NN; c += 1024, ++k) {
      int p = par[c];
      int pp = par[p];
      np[k] = pp;
      if (pp != p) ch = true;
    }
    __syncthreads();
    k = 0;
    for (int c = t; c < NN; c += 1024, ++k) par[c] = np[k];
    if (!__syncthreads_or(ch)) break;
  }
  // count roots
  int cnt = 0;
  for (int c = t; c < NN; c += 1024)
    if (live[c] && par[c] == c) cnt++;
  for (int off = 32; off > 0; off >>= 1) cnt += __shfl_down(cnt, off, 64);
  if ((t & 63) == 0 && cnt) atomicAdd(&newcnt, cnt);
  // relabel vertices + reset compbest
  for (int v = t; v < NN; v += 1024) comp[v] = par[comp[v]];
  for (int c = t; c < NN; c += 1024) cb[c] = ~0ull;
  __syncthreads();
  if (t == 0) ncomp[g] = newcnt;
}

// ---------- move tree edges to persistence 0 (slab 0; same dequant grid => exact) ----------
__global__ void k_treefix(const float* __restrict__ twbase, const unsigned* __restrict__ caps,
                          unsigned* __restrict__ Hs) {
  int g = blockIdx.y;
  unsigned* hist = Hs + (size_t)(g * NSLAB) * NBINS;
  float cap = __uint_as_float(caps[g]);
  float capmax = fmaxf(__uint_as_float(caps[0]), __uint_as_float(caps[1]));
  float scale = (float)NBINS / capmax;
  int idx = blockIdx.x * blockDim.x + threadIdx.x;
  if (idx < NN - 1) {
    float w = twbase[g * (NN - 1) + idx];
    atomicSub(&hist[bin_of(cap - w, scale)], 1u);  // may wrap; per-bin total stays >= 0
    atomicAdd(&hist[0], 1u);
  }
}

// ---------- merge 256 slabs per graph -> Hm[2][NBINS] ----------
__global__ __launch_bounds__(256) void k_merge(const unsigned* __restrict__ Hs,
                                               unsigned* __restrict__ Hm) {
  int id = blockIdx.x * 256 + threadIdx.x;  // 0 .. 2*NBINS-1
  int g = id >> 14;
  int i = id & (NBINS - 1);
  const unsigned* base = Hs + (size_t)(g * NSLAB) * NBINS + i;
  unsigned sum = 0;
  for (int s = 0; s < NSLAB; ++s) sum += base[(size_t)s * NBINS];
  Hm[id] = sum;
}

// ---------- W1: single block computes sum |running prefix| * dt ----------
__global__ __launch_bounds__(256) void k_w1(const unsigned* __restrict__ Hm,
                                            const unsigned* __restrict__ caps,
                                            float* __restrict__ out) {
  int t = threadIdx.x;
  const int PB = NBINS / 256;  // 64 bins per thread
  int base = t * PB;
  long long tsum = 0;
  for (int i = 0; i < PB; ++i)
    tsum += (long long)(int)(Hm[base + i] - Hm[NBINS + base + i]);
  int lane = t & 63, wid = t >> 6;
  long long incl = tsum;
  for (int off = 1; off < 64; off <<= 1) {
    long long o = __shfl_up(incl, off, 64);
    if (lane >= off) incl += o;
  }
  __shared__ long long wtot[4];
  if (lane == 63) wtot[wid] = incl;
  __syncthreads();
  long long run = incl - tsum;
  for (int w = 0; w < wid; ++w) run += wtot[w];
  unsigned long long local = 0;
  for (int i = 0; i < PB; ++i) {
    run += (long long)(int)(Hm[base + i] - Hm[NBINS + base + i]);
    local += (unsigned long long)(run < 0 ? -run : run);
  }
  for (int off = 32; off > 0; off >>= 1) local += __shfl_down(local, off, 64);
  __shared__ unsigned long long wl[4];
  if (lane == 0) wl[wid] = local;
  __syncthreads();
  if (t == 0) {
    float capmax = fmaxf(__uint_as_float(caps[0]), __uint_as_float(caps[1]));
    double dt = (double)capmax / (double)NBINS;
    out[0] = (float)((double)(wl[0] + wl[1] + wl[2] + wl[3]) * dt);
  }
}

__global__ void k_fail(float* out) { out[0] = -1234567.0f; }

extern "C" void kernel_launch(void* const* d_in, const int* in_sizes, int n_in,
                              void* d_out, int out_size, void* d_ws, size_t ws_size,
                              hipStream_t stream) {
  const float* x1 = (const float*)d_in[0];
  const float* x2 = (const float*)d_in[2];
  float* out = (float*)d_out;
  char* ws = (char*)d_ws;

  const size_t offQ = 0;                                        // u16 D: 64 MiB
  const size_t offS = 2ull * NN * NN * 2ull;                    // slabs: 32 MiB
  const size_t offHm = offS + 2ull * NSLAB * NBINS * 4ull;      // 128 KiB merged hist
  const size_t offHdr = offHm + 2ull * NBINS * 4ull;            // caps+qscale+qinv
  const size_t offSq = offHdr + 64;
  const size_t offTw = offSq + 2ull * NN * 4ull;
  const size_t offCb = (offTw + 2ull * (NN - 1) * 4ull + 7ull) & ~7ull;
  const size_t offSeg = offCb + 2ull * NN * 8ull;               // segmin: 1 MiB
  const size_t offCp = offSeg + 2ull * NN * 32ull * 4ull;
  const size_t offMeta = offCp + 2ull * NN * 4ull;              // mstcnt[2], ncomp[2]
  const size_t needed = offMeta + 64;
  if (ws_size < needed) {
    hipLaunchKernelGGL(k_fail, dim3(1), dim3(1), 0, stream, out);
    return;
  }

  unsigned short* Qbase = (unsigned short*)(ws + offQ);
  unsigned* Hs = (unsigned*)(ws + offS);
  // Xhi/Xlo (4 MiB) transiently live in the slab region (dead before k_hist writes it)
  unsigned short* Xhi = (unsigned short*)(ws + offS);
  unsigned short* Xlo = (unsigned short*)(ws + offS + 2ull * NN * DF * 2ull);
  unsigned* Hm = (unsigned*)(ws + offHm);
  unsigned* caps = (unsigned*)(ws + offHdr);
  float* hdrf = (float*)(ws + offHdr);
  float* sq = (float*)(ws + offSq);
  float* tw = (float*)(ws + offTw);
  unsigned long long* compbest = (unsigned long long*)(ws + offCb);
  unsigned* segmin = (unsigned*)(ws + offSeg);
  int* comp = (int*)(ws + offCp);
  int* mstcnt = (int*)(ws + offMeta);
  int* ncomp = (int*)(ws + offMeta + 8);

  hipLaunchKernelGGL(k_rownorm, dim3((2 * NN + 255) / 256), dim3(256), 0, stream, x1, x2, sq);
  hipLaunchKernelGGL(k_bound, dim3(1), dim3(256), 0, stream, sq, hdrf);
  // k_split now also does Boruvka init + caps zeroing (replaces k_binit + memset)
  hipLaunchKernelGGL(k_split, dim3((2 * NN * DF + 255) / 256), dim3(256), 0, stream,
                     x1, x2, Xhi, Xlo, comp, compbest, mstcnt, ncomp, caps);
  hipLaunchKernelGGL(k_dist, dim3(NN / 128, NN / 128, 2), dim3(256), 0, stream,
                     Xhi, Xlo, sq, hdrf, Qbase, caps);
  // k_hist BEFORE Boruvka: streams Q once for the histogram AND the segmin table
  hipLaunchKernelGGL(k_hist, dim3(2 * NSLAB), dim3(256), 0, stream,
                     Qbase, caps, hdrf, Hs, segmin);
  for (int r = 0; r < BORUVKA_ROUNDS; ++r) {
    hipLaunchKernelGGL(k_minedge, dim3(NN / 16, 2), dim3(1024), 0, stream,
                       Qbase, segmin, comp, compbest, ncomp);
    hipLaunchKernelGGL(k_hook, dim3(2), dim3(1024), 0, stream,
                       compbest, comp, hdrf, tw, mstcnt, ncomp);
  }
  hipLaunchKernelGGL(k_treefix, dim3(16, 2), dim3(256), 0, stream, tw, caps, Hs);
  hipLaunchKernelGGL(k_merge, dim3(2 * NBINS / 256), dim3(256), 0, stream, Hs, Hm);
  hipLaunchKernelGGL(k_w1, dim3(1), dim3(256), 0, stream, Hm, caps, out);
}